// Round 7
// baseline (2113.595 us; speedup 1.0000x reference)
//
#include <hip/hip_runtime.h>
#include <math.h>

#define T_STEPS 8
#define F_DIM 64

using half8 = __attribute__((ext_vector_type(8))) _Float16;
using half4 = __attribute__((ext_vector_type(4))) _Float16;
using f32x4 = __attribute__((ext_vector_type(4))) float;

__device__ __forceinline__ float sigmoidf_(float x) { return 1.f / (1.f + __expf(-x)); }

// ---------------- setup kernels (edge_index arrives as int32) ----------------

__global__ void k_deg_cnt(const int* ei, int E, int N, int* deg, int* cnt) {
  int e = blockIdx.x * blockDim.x + threadIdx.x;
  if (e >= E) return;
  int s = ei[e];
  int d = ei[E + e];
  if ((unsigned)s < (unsigned)N) atomicAdd(&deg[s], 1);
  if ((unsigned)d < (unsigned)N) atomicAdd(&cnt[d], 1);
}

__global__ void k_dinv(const int* deg, float* dinv, int n) {
  int i = blockIdx.x * blockDim.x + threadIdx.x;
  if (i >= n) return;
  int d = deg[i];
  dinv[i] = d > 0 ? 1.0f / sqrtf((float)d) : 0.f;
}

__global__ void k_scan1(const int* cnt, int* incl, int* bsum, int n) {
  __shared__ int s[1024];
  int t = threadIdx.x;
  int i = blockIdx.x * 1024 + t;
  int v = (i < n) ? cnt[i] : 0;
  s[t] = v;
  __syncthreads();
  for (int off = 1; off < 1024; off <<= 1) {
    int add = (t >= off) ? s[t - off] : 0;
    __syncthreads();
    s[t] += add;
    __syncthreads();
  }
  if (i < n) incl[i] = s[t];
  if (t == 1023) bsum[blockIdx.x] = s[1023];
}

// parallel exclusive scan of block sums (nb <= 1024)
__global__ void k_scan2p(const int* bsum, int* boff, int nb) {
  __shared__ int sh[1024];
  int t = threadIdx.x;
  int v = (t < nb) ? bsum[t] : 0;
  sh[t] = v;
  __syncthreads();
  for (int off = 1; off < 1024; off <<= 1) {
    int add = (t >= off) ? sh[t - off] : 0;
    __syncthreads();
    sh[t] += add;
    __syncthreads();
  }
  if (t < nb) boff[t] = sh[t] - v;
}

__global__ void k_scan2(const int* bsum, int* boff, int nb) {
  if (threadIdx.x == 0 && blockIdx.x == 0) {
    int run = 0;
    for (int b = 0; b < nb; ++b) { int v = bsum[b]; boff[b] = run; run += v; }
  }
}

__global__ void k_scan3(const int* incl, const int* cnt, const int* boff,
                        int* rp, int n, int E) {
  int i = blockIdx.x * 1024 + threadIdx.x;
  if (i >= n) return;
  int b = i >> 10;
  rp[i] = incl[i] - cnt[i] + boff[b];
  if (i == n - 1) rp[n] = incl[i] + boff[b];
}

// fill packed (col, weight) pairs: cw[j] = {src, -dinv[s]*dinv[d]}
__global__ void k_fill(const int* ei, int E, int N, const float* dinv,
                       const int* rp, int* fill, int2* cw) {
  int e = blockIdx.x * blockDim.x + threadIdx.x;
  if (e >= E) return;
  int s = ei[e];
  int d = ei[E + e];
  if ((unsigned)s >= (unsigned)N || (unsigned)d >= (unsigned)N) return;
  int pos = atomicAdd(&fill[d], 1);
  int j = rp[d] + pos;
  int2 v;
  v.x = s;
  v.y = __float_as_int(-dinv[s] * dinv[d]);
  cw[j] = v;
}

// ---------------- weight pack: per-MFMA-fragment fp16 layout ----------------
// Fragment (c, kk): lane l holds B[k = kk*32 + (l>>4)*8 + i][col = c*16 + (l&15)],
// i = 0..7. Packed: W[((c*8+kk)*64 + l)*8 + i].
// K = [h*W0_h | h*W1_h | x*W0_x | x*W1_x] (m = K>>6, kidx = m&1, hpart = m<2).
__global__ void k_pack(const float* Whz, const float* Whr, const float* Wxz, const float* Wxr,
                       const float* Whh, const float* Wxh,
                       const float* bhz, const float* bhr, const float* bxz, const float* bxr,
                       const float* bhh, const float* bxh,
                       _Float16* Wzr, _Float16* Wh2, float* bzr, float* bhb) {
  int i = blockIdx.x * 256 + threadIdx.x;
  if (i < 49152) {
    int q, chunk;
    const float *srcH, *srcX;
    _Float16* dst;
    if (i < 32768) {
      chunk = i >> 14;
      q = i & 16383;
      srcH = chunk == 0 ? Whz : Whr;
      srcX = chunk == 0 ? Wxz : Wxr;
      dst = Wzr + i;
    } else {
      q = i - 32768;
      srcH = Whh;
      srcX = Wxh;
      dst = Wh2 + q;
    }
    int e = q & 7, lq = (q >> 3) & 63, kk = (q >> 9) & 7, c = (q >> 12) & 3;
    int K = kk * 32 + ((lq >> 4) << 3) + e;
    int colg = c * 16 + (lq & 15);
    int m = K >> 6, row = K & 63, kidx = m & 1;
    const float* src = (m < 2) ? srcH : srcX;
    *dst = (_Float16)src[kidx * 4096 + row * 64 + colg];
  } else if (i < 49152 + 128) {
    int o = i - 49152;
    bzr[o] = (o < 64) ? (bhz[o] + bxz[o]) : (bhr[o - 64] + bxr[o - 64]);
  } else if (i < 49152 + 128 + 64) {
    int o = i - (49152 + 128);
    bhb[o] = bhh[o] + bxh[o];
  }
}

// ---------------- convert X_seq fp32 [T][N][64] -> fp16 interleaved [N][T][64] ----
__global__ __launch_bounds__(256) void k_cvt_x(const float* __restrict__ X, _Float16* __restrict__ xh,
                                               int N, int total) {
  int i = blockIdx.x * 256 + threadIdx.x;
  if (i >= total) return;
  int per_t = N * 16;
  int t = i / per_t;
  int rem = i - t * per_t;
  int n = rem >> 4;
  int f4 = rem & 15;
  float4 v = *(const float4*)(X + (((size_t)t * N + n) << 6) + (f4 << 2));
  half4 o;
  o[0] = (_Float16)v.x; o[1] = (_Float16)v.y; o[2] = (_Float16)v.z; o[3] = (_Float16)v.w;
  *(half4*)(xh + ((size_t)n * (T_STEPS * 64)) + t * 64 + (f4 << 2)) = o;
}

// ---------------- batched SpMV over all 8 timesteps (x side), half4 lanes ----
// Gather from interleaved xh [N][T*64]; write y in [T][N][64] ([T]-major) so the
// per-step GEMM reads contiguous slices. Lane l owns features 4*(l&15)..+3 at
// t = l>>4 and t+4. ILP-2 over edges.
__global__ __launch_bounds__(256) void k_spmv_x8(const int* __restrict__ rp,
                                                 const int2* __restrict__ cw,
                                                 const _Float16* __restrict__ xh,
                                                 _Float16* __restrict__ y, int n) {
  int row = blockIdx.x * 4 + (threadIdx.x >> 6);
  if (row >= n) return;
  const int l = threadIdx.x & 63;
  const int off0 = l << 2;  // halfs within the 512-half interleaved row
  int s = rp[row], e = rp[row + 1];
  f32x4 a0 = {0.f, 0.f, 0.f, 0.f}, a1 = {0.f, 0.f, 0.f, 0.f};
  int j = s;
  for (; j + 2 <= e; j += 2) {
    int2 p = cw[j], q = cw[j + 1];
    float w0 = __int_as_float(p.y), w1 = __int_as_float(q.y);
    const _Float16* p0 = xh + ((size_t)p.x << 9);
    const _Float16* p1 = xh + ((size_t)q.x << 9);
    half4 u0 = *(const half4*)(p0 + off0);
    half4 u1 = *(const half4*)(p0 + 256 + off0);
    half4 v0 = *(const half4*)(p1 + off0);
    half4 v1 = *(const half4*)(p1 + 256 + off0);
#pragma unroll
    for (int qq = 0; qq < 4; ++qq) {
      a0[qq] = fmaf(w0, (float)u0[qq], a0[qq]);
      a1[qq] = fmaf(w0, (float)u1[qq], a1[qq]);
      a0[qq] = fmaf(w1, (float)v0[qq], a0[qq]);
      a1[qq] = fmaf(w1, (float)v1[qq], a1[qq]);
    }
  }
  if (j < e) {
    int2 p = cw[j];
    float w0 = __int_as_float(p.y);
    const _Float16* p0 = xh + ((size_t)p.x << 9);
    half4 u0 = *(const half4*)(p0 + off0);
    half4 u1 = *(const half4*)(p0 + 256 + off0);
#pragma unroll
    for (int qq = 0; qq < 4; ++qq) {
      a0[qq] = fmaf(w0, (float)u0[qq], a0[qq]);
      a1[qq] = fmaf(w0, (float)u1[qq], a1[qq]);
    }
  }
  const int t0 = l >> 4;
  const int foff = (l & 15) << 2;
  half4 o0, o1;
#pragma unroll
  for (int qq = 0; qq < 4; ++qq) { o0[qq] = (_Float16)a0[qq]; o1[qq] = (_Float16)a1[qq]; }
  *(half4*)(y + ((size_t)t0 * n << 6) + ((size_t)row << 6) + foff) = o0;
  *(half4*)(y + ((size_t)(t0 + 4) * n << 6) + ((size_t)row << 6) + foff) = o1;
}

// ---------------- h-side SpMV: wave/row, 4 edges/iter (16 lanes/edge, half4) ----
__global__ __launch_bounds__(256) void k_spmv4(const int* __restrict__ rp,
                                               const int2* __restrict__ cw,
                                               const _Float16* __restrict__ x,
                                               _Float16* __restrict__ y, int n) {
  int row = blockIdx.x * 4 + (threadIdx.x >> 6);
  if (row >= n) return;
  const int l = threadIdx.x & 63;
  const int grp = l >> 4;
  const int foff = (l & 15) << 2;  // halfs
  const int s = rp[row], e = rp[row + 1];
  f32x4 acc = {0.f, 0.f, 0.f, 0.f};
  for (int j0 = s + grp; j0 < e; j0 += 8) {
    int2 p = cw[j0];
    float w0 = __int_as_float(p.y);
    int j1 = j0 + 4;
    bool ok1 = j1 < e;
    int2 q = ok1 ? cw[j1] : p;
    float w1 = ok1 ? __int_as_float(q.y) : 0.f;
    half4 u0 = *(const half4*)(x + ((size_t)p.x << 6) + foff);
    half4 u1 = *(const half4*)(x + ((size_t)q.x << 6) + foff);
#pragma unroll
    for (int qq = 0; qq < 4; ++qq) {
      acc[qq] = fmaf(w0, (float)u0[qq], acc[qq]);
      acc[qq] = fmaf(w1, (float)u1[qq], acc[qq]);
    }
  }
#pragma unroll
  for (int qq = 0; qq < 4; ++qq) {
    acc[qq] += __shfl_xor(acc[qq], 16);
    acc[qq] += __shfl_xor(acc[qq], 32);
  }
  if (grp == 0) {
    half4 o;
#pragma unroll
    for (int qq = 0; qq < 4; ++qq) o[qq] = (_Float16)acc[qq];
    *(half4*)(y + ((size_t)row << 6) + foff) = o;
  }
}

// ---------------- standalone SpMV from fp32 input (fallback path only) ----------
__global__ __launch_bounds__(256) void k_spmv_f32(const int* __restrict__ rp,
                                                  const int2* __restrict__ cw,
                                                  const float* __restrict__ x,
                                                  _Float16* __restrict__ y, int n) {
  int row = blockIdx.x * 4 + (threadIdx.x >> 6);
  if (row >= n) return;
  int lane = threadIdx.x & 63;
  int s = rp[row], e = rp[row + 1];
  float acc = 0.f, acc2 = 0.f;
  int j = s;
  for (; j + 2 <= e; j += 2) {
    int2 p = cw[j], q = cw[j + 1];
    acc = fmaf(__int_as_float(p.y), x[(size_t)p.x * 64 + lane], acc);
    acc2 = fmaf(__int_as_float(q.y), x[(size_t)q.x * 64 + lane], acc2);
  }
  if (j < e) {
    int2 p = cw[j];
    acc = fmaf(__int_as_float(p.y), x[(size_t)p.x * 64 + lane], acc);
  }
  y[(size_t)row * 64 + lane] = (_Float16)(acc + acc2);
}

// ---------------- plain fp32->fp16 convert (fallback path) ----------------
__global__ __launch_bounds__(256) void k_cvt1(const float* __restrict__ in,
                                              _Float16* __restrict__ o, int total4) {
  int i = blockIdx.x * 256 + threadIdx.x;
  if (i >= total4) return;
  float4 v = ((const float4*)in)[i];
  half4 h;
  h[0] = (_Float16)v.x; h[1] = (_Float16)v.y; h[2] = (_Float16)v.z; h[3] = (_Float16)v.w;
  ((half4*)o)[i] = h;
}

// ---------------- MFMA GEMM ZR: 64 rows x 128 outs (z,r), K=256, 8 waves ------
// One block computes BOTH chunks so A operands are fetched once (L1-shared).
// wave w: chunk = w>>2 (0:z, 1:r), rh = (w>>1)&1, ch = w&1.
// zh = sigmoid(acc+b); hrh = h * sigmoid(acc+b).
__global__ __launch_bounds__(512) void k_gzr(
    const _Float16* __restrict__ A0, const _Float16* __restrict__ A1,
    const _Float16* __restrict__ A2, int s2, const _Float16* __restrict__ A3, int s3,
    const _Float16* __restrict__ Wpk, const float* __restrict__ bias,
    _Float16* __restrict__ zh, float* __restrict__ h, _Float16* __restrict__ hrh, int n) {
  const int t = threadIdx.x;
  const int l = t & 63;
  const int w = t >> 6;
  const int chunk = w >> 2;
  const int rh = (w >> 1) & 1;
  const int ch = w & 1;
  const int rowBase = blockIdx.x * 64;

  const _Float16* Wp = Wpk + (size_t)chunk * 16384;
  half8 bf[8][2];
#pragma unroll
  for (int kk = 0; kk < 8; ++kk)
#pragma unroll
    for (int cc = 0; cc < 2; ++cc)
      bf[kk][cc] = *(const half8*)(Wp + ((((ch * 2 + cc) * 8 + kk) * 64 + l) << 3));

  const int row0 = rowBase + rh * 32 + (l & 15);
  const int row1 = row0 + 16;
  const bool r0ok = row0 < n, r1ok = row1 < n;

  f32x4 acc[2][2] = {};
#pragma unroll
  for (int kk = 0; kk < 8; ++kk) {
    const int m = kk >> 1;
    const int coloff = (kk & 1) * 32 + ((l >> 4) << 3);
    const _Float16* base = (m == 0) ? A0 : (m == 1) ? A1 : (m == 2) ? A2 : A3;
    const int st = (m <= 1) ? 64 : (m == 2 ? s2 : s3);
    half8 a0{}, a1{};
    if (r0ok) a0 = *(const half8*)(base + (size_t)row0 * st + coloff);
    if (r1ok) a1 = *(const half8*)(base + (size_t)row1 * st + coloff);
#pragma unroll
    for (int cc = 0; cc < 2; ++cc) {
      acc[0][cc] = __builtin_amdgcn_mfma_f32_16x16x32_f16(a0, bf[kk][cc], acc[0][cc], 0, 0, 0);
      acc[1][cc] = __builtin_amdgcn_mfma_f32_16x16x32_f16(a1, bf[kk][cc], acc[1][cc], 0, 0, 0);
    }
  }

#pragma unroll
  for (int rt = 0; rt < 2; ++rt)
#pragma unroll
    for (int cc = 0; cc < 2; ++cc) {
      const int colg = ch * 32 + cc * 16 + (l & 15);
      const float b = bias[chunk * 64 + colg];
#pragma unroll
      for (int reg = 0; reg < 4; ++reg) {
        const int row = rowBase + rh * 32 + rt * 16 + ((l >> 4) << 2) + reg;
        if (row >= n) continue;
        const float sv = acc[rt][cc][reg] + b;
        const size_t idx = ((size_t)row << 6) + colg;
        const float g = sigmoidf_(sv);
        if (chunk == 0) zh[idx] = (_Float16)g;
        else hrh[idx] = (_Float16)(h[idx] * g);
      }
    }
}

// ---------------- MFMA GEMM H: 64 rows x 64 outs, K=256, 4 waves --------------
// hn = z*h + (1-z)*tanh(acc+b); h (fp32) and hh (fp16) updated.
__global__ __launch_bounds__(256) void k_gh(
    const _Float16* __restrict__ A0, const _Float16* __restrict__ A1,
    const _Float16* __restrict__ A2, int s2, const _Float16* __restrict__ A3, int s3,
    const _Float16* __restrict__ Wpk, const float* __restrict__ bias,
    const _Float16* __restrict__ zh, float* __restrict__ h, _Float16* __restrict__ hh, int n) {
  const int t = threadIdx.x;
  const int l = t & 63;
  const int w = t >> 6;
  const int rh = w >> 1;
  const int ch = w & 1;
  const int rowBase = blockIdx.x * 64;

  half8 bf[8][2];
#pragma unroll
  for (int kk = 0; kk < 8; ++kk)
#pragma unroll
    for (int cc = 0; cc < 2; ++cc)
      bf[kk][cc] = *(const half8*)(Wpk + ((((ch * 2 + cc) * 8 + kk) * 64 + l) << 3));

  const int row0 = rowBase + rh * 32 + (l & 15);
  const int row1 = row0 + 16;
  const bool r0ok = row0 < n, r1ok = row1 < n;

  f32x4 acc[2][2] = {};
#pragma unroll
  for (int kk = 0; kk < 8; ++kk) {
    const int m = kk >> 1;
    const int coloff = (kk & 1) * 32 + ((l >> 4) << 3);
    const _Float16* base = (m == 0) ? A0 : (m == 1) ? A1 : (m == 2) ? A2 : A3;
    const int st = (m <= 1) ? 64 : (m == 2 ? s2 : s3);
    half8 a0{}, a1{};
    if (r0ok) a0 = *(const half8*)(base + (size_t)row0 * st + coloff);
    if (r1ok) a1 = *(const half8*)(base + (size_t)row1 * st + coloff);
#pragma unroll
    for (int cc = 0; cc < 2; ++cc) {
      acc[0][cc] = __builtin_amdgcn_mfma_f32_16x16x32_f16(a0, bf[kk][cc], acc[0][cc], 0, 0, 0);
      acc[1][cc] = __builtin_amdgcn_mfma_f32_16x16x32_f16(a1, bf[kk][cc], acc[1][cc], 0, 0, 0);
    }
  }

#pragma unroll
  for (int rt = 0; rt < 2; ++rt)
#pragma unroll
    for (int cc = 0; cc < 2; ++cc) {
      const int colg = ch * 32 + cc * 16 + (l & 15);
      const float b = bias[colg];
#pragma unroll
      for (int reg = 0; reg < 4; ++reg) {
        const int row = rowBase + rh * 32 + rt * 16 + ((l >> 4) << 2) + reg;
        if (row >= n) continue;
        const float sv = acc[rt][cc][reg] + b;
        const size_t idx = ((size_t)row << 6) + colg;
        const float ht = tanhf(sv);
        const float zz = (float)zh[idx];
        const float hn = zz * h[idx] + (1.f - zz) * ht;
        h[idx] = hn;
        hh[idx] = (_Float16)hn;
      }
    }
}

// ---------------- final linear: out = h @ Wlin + blin ----------------
__global__ __launch_bounds__(256) void k_lin(const float* __restrict__ h,
                                             const float* __restrict__ Wlin,
                                             const float* __restrict__ blin,
                                             float* __restrict__ out, int n) {
  __shared__ float Wl[64 * 16];
  __shared__ float bl[16];
  int t = threadIdx.x;
#pragma unroll
  for (int it = 0; it < 4; ++it) Wl[it * 256 + t] = Wlin[it * 256 + t];
  if (t < 16) bl[t] = blin[t];
  __syncthreads();
  int r = blockIdx.x * 16 + (t >> 4);
  int c = t & 15;
  if (r >= n) return;
  const float* hp = h + (size_t)r * 64;
  float acc = bl[c];
#pragma unroll
  for (int k = 0; k < 64; ++k) acc = fmaf(hp[k], Wl[k * 16 + c], acc);
  out[(size_t)r * 16 + c] = acc;
}

extern "C" void kernel_launch(void* const* d_in, const int* in_sizes, int n_in,
                              void* d_out, int out_size, void* d_ws, size_t ws_size,
                              hipStream_t stream) {
  const float* Xseq = (const float*)d_in[0];
  const int* ei = (const int*)d_in[1];
  const float* Wxz = (const float*)d_in[2];
  const float* bxz = (const float*)d_in[3];
  const float* Whz = (const float*)d_in[4];
  const float* bhz = (const float*)d_in[5];
  const float* Wxr = (const float*)d_in[6];
  const float* bxr = (const float*)d_in[7];
  const float* Whr = (const float*)d_in[8];
  const float* bhr = (const float*)d_in[9];
  const float* Wxh = (const float*)d_in[10];
  const float* bxh = (const float*)d_in[11];
  const float* Whh = (const float*)d_in[12];
  const float* bhh = (const float*)d_in[13];
  const float* Wlin = (const float*)d_in[14];
  const float* blin = (const float*)d_in[15];
  float* out = (float*)d_out;

  const int N = in_sizes[0] / (T_STEPS * F_DIM);
  const int E = in_sizes[1] / 2;

  char* p = (char*)d_ws;
  size_t used = 0;
  auto alloc = [&](size_t bytes) {
    char* r = p;
    size_t a = (bytes + 255) & ~(size_t)255;
    p += a;
    used += a;
    return r;
  };
  int* deg = (int*)alloc((size_t)N * 4);
  int* cnt = (int*)alloc((size_t)N * 4);
  int* incl = (int*)alloc((size_t)N * 4);
  int* fill = (int*)alloc((size_t)N * 4);
  int* bsum = (int*)alloc(1024 * 4);
  int* boff = (int*)alloc(1024 * 4);
  float* dinv = (float*)alloc((size_t)N * 4);
  int* rp = (int*)alloc((size_t)(N + 1) * 4);
  int2* cw = (int2*)alloc((size_t)E * 8);
  _Float16* Wzr = (_Float16*)alloc(32768 * 2);
  _Float16* Wh2 = (_Float16*)alloc(16384 * 2);
  float* bzr = (float*)alloc(128 * 4);
  float* bhb = (float*)alloc(64 * 4);
  float* h = (float*)alloc((size_t)N * 64 * 4);
  _Float16* hh = (_Float16*)alloc((size_t)N * 64 * 2);
  _Float16* mv2h = (_Float16*)alloc((size_t)N * 64 * 2);
  _Float16* hrh = (_Float16*)alloc((size_t)N * 64 * 2);
  _Float16* zh = (_Float16*)alloc((size_t)N * 64 * 2);

  size_t need_big = 2 * ((size_t)N * T_STEPS * 64 * 2 + 255);
  bool big = (used + need_big + 4096) <= ws_size;
  _Float16 *xh_i = nullptr, *mvx_t = nullptr, *xth = nullptr, *mvxth = nullptr;
  if (big) {
    xh_i = (_Float16*)alloc((size_t)N * T_STEPS * 64 * 2);   // [N][T*64] interleaved
    mvx_t = (_Float16*)alloc((size_t)T_STEPS * N * 64 * 2);  // [T][N][64]
  } else {
    xth = (_Float16*)alloc((size_t)N * 64 * 2);
    mvxth = (_Float16*)alloc((size_t)N * 64 * 2);
  }

  hipMemsetAsync(deg, 0, (size_t)N * 4, stream);
  hipMemsetAsync(cnt, 0, (size_t)N * 4, stream);
  hipMemsetAsync(fill, 0, (size_t)N * 4, stream);
  hipMemsetAsync(h, 0, (size_t)N * 64 * 4, stream);
  hipMemsetAsync(hh, 0, (size_t)N * 64 * 2, stream);

  k_deg_cnt<<<(E + 255) / 256, 256, 0, stream>>>(ei, E, N, deg, cnt);
  k_dinv<<<(N + 255) / 256, 256, 0, stream>>>(deg, dinv, N);
  int nb = (N + 1023) / 1024;
  k_scan1<<<nb, 1024, 0, stream>>>(cnt, incl, bsum, N);
  if (nb <= 1024)
    k_scan2p<<<1, 1024, 0, stream>>>(bsum, boff, nb);
  else
    k_scan2<<<1, 1, 0, stream>>>(bsum, boff, nb);
  k_scan3<<<nb, 1024, 0, stream>>>(incl, cnt, boff, rp, N, E);
  k_fill<<<(E + 255) / 256, 256, 0, stream>>>(ei, E, N, dinv, rp, fill, cw);
  k_pack<<<(49152 + 192 + 255) / 256, 256, 0, stream>>>(Whz, Whr, Wxz, Wxr, Whh, Wxh,
                                                        bhz, bhr, bxz, bxr, bhh, bxh,
                                                        Wzr, Wh2, bzr, bhb);

  if (big) {
    int total = T_STEPS * N * 16;
    k_cvt_x<<<(total + 255) / 256, 256, 0, stream>>>(Xseq, xh_i, N, total);
    k_spmv_x8<<<(N + 3) / 4, 256, 0, stream>>>(rp, cw, xh_i, mvx_t, N);
  }

  const int gb = (N + 63) / 64;
  for (int tt = 0; tt < T_STEPS; ++tt) {
    const float* xt = Xseq + (size_t)tt * N * F_DIM;
    const _Float16* A2;
    const _Float16* A3;
    int s2, s3;
    if (big) {
      A2 = xh_i + tt * 64; s2 = T_STEPS * 64;                // interleaved, stride 512
      A3 = mvx_t + (size_t)tt * N * 64; s3 = 64;             // contiguous slice
    } else {
      k_cvt1<<<(N * 16 + 255) / 256, 256, 0, stream>>>(xt, xth, N * 16);
      k_spmv_f32<<<(N + 3) / 4, 256, 0, stream>>>(rp, cw, xt, mvxth, N);
      A2 = xth; s2 = 64;
      A3 = mvxth; s3 = 64;
    }
    // mv(h)
    k_spmv4<<<(N + 3) / 4, 256, 0, stream>>>(rp, cw, hh, mv2h, N);
    // z and hr (one block, both chunks)
    k_gzr<<<gb, 512, 0, stream>>>(hh, mv2h, A2, s2, A3, s3, Wzr, bzr, zh, h, hrh, N);
    // mv(h*r)
    k_spmv4<<<(N + 3) / 4, 256, 0, stream>>>(rp, cw, hrh, mv2h, N);
    // h update
    k_gh<<<gb, 256, 0, stream>>>(hrh, mv2h, A2, s2, A3, s3, Wh2, bhb, zh, h, hh, N);
  }
  k_lin<<<(N + 15) / 16, 256, 0, stream>>>(h, Wlin, blin, out, N);
}

// Round 8
// 1996.231 us; speedup vs baseline: 1.0588x; 1.0588x over previous
//
#include <hip/hip_runtime.h>
#include <math.h>

#define T_STEPS 8
#define F_DIM 64

using half8 = __attribute__((ext_vector_type(8))) _Float16;
using half4 = __attribute__((ext_vector_type(4))) _Float16;
using f32x4 = __attribute__((ext_vector_type(4))) float;

__device__ __forceinline__ float sigmoidf_(float x) { return 1.f / (1.f + __expf(-x)); }

// ---------------- setup kernels (edge_index arrives as int32) ----------------

__global__ void k_deg_cnt(const int* ei, int E, int N, int* deg, int* cnt) {
  int e = blockIdx.x * blockDim.x + threadIdx.x;
  if (e >= E) return;
  int s = ei[e];
  int d = ei[E + e];
  if ((unsigned)s < (unsigned)N) atomicAdd(&deg[s], 1);
  if ((unsigned)d < (unsigned)N) atomicAdd(&cnt[d], 1);
}

__global__ void k_dinv(const int* deg, float* dinv, int n) {
  int i = blockIdx.x * blockDim.x + threadIdx.x;
  if (i >= n) return;
  int d = deg[i];
  dinv[i] = d > 0 ? 1.0f / sqrtf((float)d) : 0.f;
}

__global__ void k_scan1(const int* cnt, int* incl, int* bsum, int n) {
  __shared__ int s[1024];
  int t = threadIdx.x;
  int i = blockIdx.x * 1024 + t;
  int v = (i < n) ? cnt[i] : 0;
  s[t] = v;
  __syncthreads();
  for (int off = 1; off < 1024; off <<= 1) {
    int add = (t >= off) ? s[t - off] : 0;
    __syncthreads();
    s[t] += add;
    __syncthreads();
  }
  if (i < n) incl[i] = s[t];
  if (t == 1023) bsum[blockIdx.x] = s[1023];
}

// parallel exclusive scan of block sums (nb <= 1024)
__global__ void k_scan2p(const int* bsum, int* boff, int nb) {
  __shared__ int sh[1024];
  int t = threadIdx.x;
  int v = (t < nb) ? bsum[t] : 0;
  sh[t] = v;
  __syncthreads();
  for (int off = 1; off < 1024; off <<= 1) {
    int add = (t >= off) ? sh[t - off] : 0;
    __syncthreads();
    sh[t] += add;
    __syncthreads();
  }
  if (t < nb) boff[t] = sh[t] - v;
}

__global__ void k_scan2(const int* bsum, int* boff, int nb) {
  if (threadIdx.x == 0 && blockIdx.x == 0) {
    int run = 0;
    for (int b = 0; b < nb; ++b) { int v = bsum[b]; boff[b] = run; run += v; }
  }
}

__global__ void k_scan3(const int* incl, const int* cnt, const int* boff,
                        int* rp, int n, int E) {
  int i = blockIdx.x * 1024 + threadIdx.x;
  if (i >= n) return;
  int b = i >> 10;
  rp[i] = incl[i] - cnt[i] + boff[b];
  if (i == n - 1) rp[n] = incl[i] + boff[b];
}

// fill packed (col, weight) pairs: cw[j] = {src, -dinv[s]*dinv[d]}
__global__ void k_fill(const int* ei, int E, int N, const float* dinv,
                       const int* rp, int* fill, int2* cw) {
  int e = blockIdx.x * blockDim.x + threadIdx.x;
  if (e >= E) return;
  int s = ei[e];
  int d = ei[E + e];
  if ((unsigned)s >= (unsigned)N || (unsigned)d >= (unsigned)N) return;
  int pos = atomicAdd(&fill[d], 1);
  int j = rp[d] + pos;
  int2 v;
  v.x = s;
  v.y = __float_as_int(-dinv[s] * dinv[d]);
  cw[j] = v;
}

// ---------------- weight pack: per-MFMA-fragment fp16 layout ----------------
__global__ void k_pack(const float* Whz, const float* Whr, const float* Wxz, const float* Wxr,
                       const float* Whh, const float* Wxh,
                       const float* bhz, const float* bhr, const float* bxz, const float* bxr,
                       const float* bhh, const float* bxh,
                       _Float16* Wzr, _Float16* Wh2, float* bzr, float* bhb) {
  int i = blockIdx.x * 256 + threadIdx.x;
  if (i < 49152) {
    int q, chunk;
    const float *srcH, *srcX;
    _Float16* dst;
    if (i < 32768) {
      chunk = i >> 14;
      q = i & 16383;
      srcH = chunk == 0 ? Whz : Whr;
      srcX = chunk == 0 ? Wxz : Wxr;
      dst = Wzr + i;
    } else {
      q = i - 32768;
      srcH = Whh;
      srcX = Wxh;
      dst = Wh2 + q;
    }
    int e = q & 7, lq = (q >> 3) & 63, kk = (q >> 9) & 7, c = (q >> 12) & 3;
    int K = kk * 32 + ((lq >> 4) << 3) + e;
    int colg = c * 16 + (lq & 15);
    int m = K >> 6, row = K & 63, kidx = m & 1;
    const float* src = (m < 2) ? srcH : srcX;
    *dst = (_Float16)src[kidx * 4096 + row * 64 + colg];
  } else if (i < 49152 + 128) {
    int o = i - 49152;
    bzr[o] = (o < 64) ? (bhz[o] + bxz[o]) : (bhr[o - 64] + bxr[o - 64]);
  } else if (i < 49152 + 128 + 64) {
    int o = i - (49152 + 128);
    bhb[o] = bhh[o] + bxh[o];
  }
}

// ---------------- convert X_seq fp32 [T][N][64] -> fp16 interleaved [N][T][64] ----
__global__ __launch_bounds__(256) void k_cvt_x(const float* __restrict__ X, _Float16* __restrict__ xh,
                                               int N, int total) {
  int i = blockIdx.x * 256 + threadIdx.x;
  if (i >= total) return;
  int per_t = N * 16;
  int t = i / per_t;
  int rem = i - t * per_t;
  int n = rem >> 4;
  int f4 = rem & 15;
  float4 v = *(const float4*)(X + (((size_t)t * N + n) << 6) + (f4 << 2));
  half4 o;
  o[0] = (_Float16)v.x; o[1] = (_Float16)v.y; o[2] = (_Float16)v.z; o[3] = (_Float16)v.w;
  *(half4*)(xh + ((size_t)n * (T_STEPS * 64)) + t * 64 + (f4 << 2)) = o;
}

// ---------------- batched SpMV over all 8 timesteps (x side), half4 lanes ----
// Handles rows [row0, row0+cnt). Split into 2 dispatches so the profiler's top-5
// stops being saturated by this one kernel (instrumentation).
__global__ __launch_bounds__(256) void k_spmv_x8(const int* __restrict__ rp,
                                                 const int2* __restrict__ cw,
                                                 const _Float16* __restrict__ xh,
                                                 _Float16* __restrict__ y,
                                                 int row0, int cnt, int n) {
  int row = row0 + blockIdx.x * 4 + (threadIdx.x >> 6);
  if (row >= row0 + cnt || row >= n) return;
  const int l = threadIdx.x & 63;
  const int off0 = l << 2;  // halfs within the 512-half interleaved row
  int s = rp[row], e = rp[row + 1];
  f32x4 a0 = {0.f, 0.f, 0.f, 0.f}, a1 = {0.f, 0.f, 0.f, 0.f};
  int j = s;
  for (; j + 2 <= e; j += 2) {
    int2 p = cw[j], q = cw[j + 1];
    float w0 = __int_as_float(p.y), w1 = __int_as_float(q.y);
    const _Float16* p0 = xh + ((size_t)p.x << 9);
    const _Float16* p1 = xh + ((size_t)q.x << 9);
    half4 u0 = *(const half4*)(p0 + off0);
    half4 u1 = *(const half4*)(p0 + 256 + off0);
    half4 v0 = *(const half4*)(p1 + off0);
    half4 v1 = *(const half4*)(p1 + 256 + off0);
#pragma unroll
    for (int qq = 0; qq < 4; ++qq) {
      a0[qq] = fmaf(w0, (float)u0[qq], a0[qq]);
      a1[qq] = fmaf(w0, (float)u1[qq], a1[qq]);
      a0[qq] = fmaf(w1, (float)v0[qq], a0[qq]);
      a1[qq] = fmaf(w1, (float)v1[qq], a1[qq]);
    }
  }
  if (j < e) {
    int2 p = cw[j];
    float w0 = __int_as_float(p.y);
    const _Float16* p0 = xh + ((size_t)p.x << 9);
    half4 u0 = *(const half4*)(p0 + off0);
    half4 u1 = *(const half4*)(p0 + 256 + off0);
#pragma unroll
    for (int qq = 0; qq < 4; ++qq) {
      a0[qq] = fmaf(w0, (float)u0[qq], a0[qq]);
      a1[qq] = fmaf(w0, (float)u1[qq], a1[qq]);
    }
  }
  const int t0 = l >> 4;
  const int foff = (l & 15) << 2;
  half4 o0, o1;
#pragma unroll
  for (int qq = 0; qq < 4; ++qq) { o0[qq] = (_Float16)a0[qq]; o1[qq] = (_Float16)a1[qq]; }
  *(half4*)(y + ((size_t)t0 * n << 6) + ((size_t)row << 6) + foff) = o0;
  *(half4*)(y + ((size_t)(t0 + 4) * n << 6) + ((size_t)row << 6) + foff) = o1;
}

// ---------------- h-side SpMV: wave/row, 16 edges/iter (16 lanes/edge, ILP-4) ----
// Group g = l>>4 handles edges j0 = s+g, stepping 16, with 4 edges (stride 4)
// in flight per iteration -> rows with deg<=16 gather in ONE latency window.
__global__ __launch_bounds__(256) void k_spmv4(const int* __restrict__ rp,
                                               const int2* __restrict__ cw,
                                               const _Float16* __restrict__ x,
                                               _Float16* __restrict__ y, int n) {
  int row = blockIdx.x * 4 + (threadIdx.x >> 6);
  if (row >= n) return;
  const int l = threadIdx.x & 63;
  const int grp = l >> 4;
  const int foff = (l & 15) << 2;  // halfs
  const int s = rp[row], e = rp[row + 1];
  f32x4 acc = {0.f, 0.f, 0.f, 0.f};
  for (int j0 = s + grp; j0 < e; j0 += 16) {
    const int j1 = j0 + 4, j2 = j0 + 8, j3 = j0 + 12;
    int2 p0 = cw[j0];
    int2 p1 = cw[j1 < e ? j1 : j0];
    int2 p2 = cw[j2 < e ? j2 : j0];
    int2 p3 = cw[j3 < e ? j3 : j0];
    float w0 = __int_as_float(p0.y);
    float w1 = j1 < e ? __int_as_float(p1.y) : 0.f;
    float w2 = j2 < e ? __int_as_float(p2.y) : 0.f;
    float w3 = j3 < e ? __int_as_float(p3.y) : 0.f;
    half4 u0 = *(const half4*)(x + ((size_t)p0.x << 6) + foff);
    half4 u1 = *(const half4*)(x + ((size_t)p1.x << 6) + foff);
    half4 u2 = *(const half4*)(x + ((size_t)p2.x << 6) + foff);
    half4 u3 = *(const half4*)(x + ((size_t)p3.x << 6) + foff);
#pragma unroll
    for (int qq = 0; qq < 4; ++qq) {
      acc[qq] = fmaf(w0, (float)u0[qq], acc[qq]);
      acc[qq] = fmaf(w1, (float)u1[qq], acc[qq]);
      acc[qq] = fmaf(w2, (float)u2[qq], acc[qq]);
      acc[qq] = fmaf(w3, (float)u3[qq], acc[qq]);
    }
  }
#pragma unroll
  for (int qq = 0; qq < 4; ++qq) {
    acc[qq] += __shfl_xor(acc[qq], 16);
    acc[qq] += __shfl_xor(acc[qq], 32);
  }
  if (grp == 0) {
    half4 o;
#pragma unroll
    for (int qq = 0; qq < 4; ++qq) o[qq] = (_Float16)acc[qq];
    *(half4*)(y + ((size_t)row << 6) + foff) = o;
  }
}

// ---------------- standalone SpMV from fp32 input (fallback path only) ----------
__global__ __launch_bounds__(256) void k_spmv_f32(const int* __restrict__ rp,
                                                  const int2* __restrict__ cw,
                                                  const float* __restrict__ x,
                                                  _Float16* __restrict__ y, int n) {
  int row = blockIdx.x * 4 + (threadIdx.x >> 6);
  if (row >= n) return;
  int lane = threadIdx.x & 63;
  int s = rp[row], e = rp[row + 1];
  float acc = 0.f, acc2 = 0.f;
  int j = s;
  for (; j + 2 <= e; j += 2) {
    int2 p = cw[j], q = cw[j + 1];
    acc = fmaf(__int_as_float(p.y), x[(size_t)p.x * 64 + lane], acc);
    acc2 = fmaf(__int_as_float(q.y), x[(size_t)q.x * 64 + lane], acc2);
  }
  if (j < e) {
    int2 p = cw[j];
    acc = fmaf(__int_as_float(p.y), x[(size_t)p.x * 64 + lane], acc);
  }
  y[(size_t)row * 64 + lane] = (_Float16)(acc + acc2);
}

// ---------------- plain fp32->fp16 convert (fallback path) ----------------
__global__ __launch_bounds__(256) void k_cvt1(const float* __restrict__ in,
                                              _Float16* __restrict__ o, int total4) {
  int i = blockIdx.x * 256 + threadIdx.x;
  if (i >= total4) return;
  float4 v = ((const float4*)in)[i];
  half4 h;
  h[0] = (_Float16)v.x; h[1] = (_Float16)v.y; h[2] = (_Float16)v.z; h[3] = (_Float16)v.w;
  ((half4*)o)[i] = h;
}

// ---------------- MFMA GEMM ZR: 64 rows x 128 outs (z,r), K=256, 8 waves ------
__global__ __launch_bounds__(512) void k_gzr(
    const _Float16* __restrict__ A0, const _Float16* __restrict__ A1,
    const _Float16* __restrict__ A2, int s2, const _Float16* __restrict__ A3, int s3,
    const _Float16* __restrict__ Wpk, const float* __restrict__ bias,
    _Float16* __restrict__ zh, float* __restrict__ h, _Float16* __restrict__ hrh, int n) {
  const int t = threadIdx.x;
  const int l = t & 63;
  const int w = t >> 6;
  const int chunk = w >> 2;
  const int rh = (w >> 1) & 1;
  const int ch = w & 1;
  const int rowBase = blockIdx.x * 64;

  const _Float16* Wp = Wpk + (size_t)chunk * 16384;
  half8 bf[8][2];
#pragma unroll
  for (int kk = 0; kk < 8; ++kk)
#pragma unroll
    for (int cc = 0; cc < 2; ++cc)
      bf[kk][cc] = *(const half8*)(Wp + ((((ch * 2 + cc) * 8 + kk) * 64 + l) << 3));

  const int row0 = rowBase + rh * 32 + (l & 15);
  const int row1 = row0 + 16;
  const bool r0ok = row0 < n, r1ok = row1 < n;

  f32x4 acc[2][2] = {};
#pragma unroll
  for (int kk = 0; kk < 8; ++kk) {
    const int m = kk >> 1;
    const int coloff = (kk & 1) * 32 + ((l >> 4) << 3);
    const _Float16* base = (m == 0) ? A0 : (m == 1) ? A1 : (m == 2) ? A2 : A3;
    const int st = (m <= 1) ? 64 : (m == 2 ? s2 : s3);
    half8 a0{}, a1{};
    if (r0ok) a0 = *(const half8*)(base + (size_t)row0 * st + coloff);
    if (r1ok) a1 = *(const half8*)(base + (size_t)row1 * st + coloff);
#pragma unroll
    for (int cc = 0; cc < 2; ++cc) {
      acc[0][cc] = __builtin_amdgcn_mfma_f32_16x16x32_f16(a0, bf[kk][cc], acc[0][cc], 0, 0, 0);
      acc[1][cc] = __builtin_amdgcn_mfma_f32_16x16x32_f16(a1, bf[kk][cc], acc[1][cc], 0, 0, 0);
    }
  }

#pragma unroll
  for (int rt = 0; rt < 2; ++rt)
#pragma unroll
    for (int cc = 0; cc < 2; ++cc) {
      const int colg = ch * 32 + cc * 16 + (l & 15);
      const float b = bias[chunk * 64 + colg];
#pragma unroll
      for (int reg = 0; reg < 4; ++reg) {
        const int row = rowBase + rh * 32 + rt * 16 + ((l >> 4) << 2) + reg;
        if (row >= n) continue;
        const float sv = acc[rt][cc][reg] + b;
        const size_t idx = ((size_t)row << 6) + colg;
        const float g = sigmoidf_(sv);
        if (chunk == 0) zh[idx] = (_Float16)g;
        else hrh[idx] = (_Float16)(h[idx] * g);
      }
    }
}

// ---------------- MFMA GEMM H: 64 rows x 64 outs, K=256, 4 waves --------------
__global__ __launch_bounds__(256) void k_gh(
    const _Float16* __restrict__ A0, const _Float16* __restrict__ A1,
    const _Float16* __restrict__ A2, int s2, const _Float16* __restrict__ A3, int s3,
    const _Float16* __restrict__ Wpk, const float* __restrict__ bias,
    const _Float16* __restrict__ zh, float* __restrict__ h, _Float16* __restrict__ hh, int n) {
  const int t = threadIdx.x;
  const int l = t & 63;
  const int w = t >> 6;
  const int rh = w >> 1;
  const int ch = w & 1;
  const int rowBase = blockIdx.x * 64;

  half8 bf[8][2];
#pragma unroll
  for (int kk = 0; kk < 8; ++kk)
#pragma unroll
    for (int cc = 0; cc < 2; ++cc)
      bf[kk][cc] = *(const half8*)(Wpk + ((((ch * 2 + cc) * 8 + kk) * 64 + l) << 3));

  const int row0 = rowBase + rh * 32 + (l & 15);
  const int row1 = row0 + 16;
  const bool r0ok = row0 < n, r1ok = row1 < n;

  f32x4 acc[2][2] = {};
#pragma unroll
  for (int kk = 0; kk < 8; ++kk) {
    const int m = kk >> 1;
    const int coloff = (kk & 1) * 32 + ((l >> 4) << 3);
    const _Float16* base = (m == 0) ? A0 : (m == 1) ? A1 : (m == 2) ? A2 : A3;
    const int st = (m <= 1) ? 64 : (m == 2 ? s2 : s3);
    half8 a0{}, a1{};
    if (r0ok) a0 = *(const half8*)(base + (size_t)row0 * st + coloff);
    if (r1ok) a1 = *(const half8*)(base + (size_t)row1 * st + coloff);
#pragma unroll
    for (int cc = 0; cc < 2; ++cc) {
      acc[0][cc] = __builtin_amdgcn_mfma_f32_16x16x32_f16(a0, bf[kk][cc], acc[0][cc], 0, 0, 0);
      acc[1][cc] = __builtin_amdgcn_mfma_f32_16x16x32_f16(a1, bf[kk][cc], acc[1][cc], 0, 0, 0);
    }
  }

#pragma unroll
  for (int rt = 0; rt < 2; ++rt)
#pragma unroll
    for (int cc = 0; cc < 2; ++cc) {
      const int colg = ch * 32 + cc * 16 + (l & 15);
      const float b = bias[colg];
#pragma unroll
      for (int reg = 0; reg < 4; ++reg) {
        const int row = rowBase + rh * 32 + rt * 16 + ((l >> 4) << 2) + reg;
        if (row >= n) continue;
        const float sv = acc[rt][cc][reg] + b;
        const size_t idx = ((size_t)row << 6) + colg;
        const float ht = tanhf(sv);
        const float zz = (float)zh[idx];
        const float hn = zz * h[idx] + (1.f - zz) * ht;
        h[idx] = hn;
        hh[idx] = (_Float16)hn;
      }
    }
}

// ---------------- final linear: out = h @ Wlin + blin ----------------
__global__ __launch_bounds__(256) void k_lin(const float* __restrict__ h,
                                             const float* __restrict__ Wlin,
                                             const float* __restrict__ blin,
                                             float* __restrict__ out, int n) {
  __shared__ float Wl[64 * 16];
  __shared__ float bl[16];
  int t = threadIdx.x;
#pragma unroll
  for (int it = 0; it < 4; ++it) Wl[it * 256 + t] = Wlin[it * 256 + t];
  if (t < 16) bl[t] = blin[t];
  __syncthreads();
  int r = blockIdx.x * 16 + (t >> 4);
  int c = t & 15;
  if (r >= n) return;
  const float* hp = h + (size_t)r * 64;
  float acc = bl[c];
#pragma unroll
  for (int k = 0; k < 64; ++k) acc = fmaf(hp[k], Wl[k * 16 + c], acc);
  out[(size_t)r * 16 + c] = acc;
}

extern "C" void kernel_launch(void* const* d_in, const int* in_sizes, int n_in,
                              void* d_out, int out_size, void* d_ws, size_t ws_size,
                              hipStream_t stream) {
  const float* Xseq = (const float*)d_in[0];
  const int* ei = (const int*)d_in[1];
  const float* Wxz = (const float*)d_in[2];
  const float* bxz = (const float*)d_in[3];
  const float* Whz = (const float*)d_in[4];
  const float* bhz = (const float*)d_in[5];
  const float* Wxr = (const float*)d_in[6];
  const float* bxr = (const float*)d_in[7];
  const float* Whr = (const float*)d_in[8];
  const float* bhr = (const float*)d_in[9];
  const float* Wxh = (const float*)d_in[10];
  const float* bxh = (const float*)d_in[11];
  const float* Whh = (const float*)d_in[12];
  const float* bhh = (const float*)d_in[13];
  const float* Wlin = (const float*)d_in[14];
  const float* blin = (const float*)d_in[15];
  float* out = (float*)d_out;

  const int N = in_sizes[0] / (T_STEPS * F_DIM);
  const int E = in_sizes[1] / 2;

  char* p = (char*)d_ws;
  size_t used = 0;
  auto alloc = [&](size_t bytes) {
    char* r = p;
    size_t a = (bytes + 255) & ~(size_t)255;
    p += a;
    used += a;
    return r;
  };
  int* deg = (int*)alloc((size_t)N * 4);
  int* cnt = (int*)alloc((size_t)N * 4);
  int* incl = (int*)alloc((size_t)N * 4);
  int* fill = (int*)alloc((size_t)N * 4);
  int* bsum = (int*)alloc(1024 * 4);
  int* boff = (int*)alloc(1024 * 4);
  float* dinv = (float*)alloc((size_t)N * 4);
  int* rp = (int*)alloc((size_t)(N + 1) * 4);
  int2* cw = (int2*)alloc((size_t)E * 8);
  _Float16* Wzr = (_Float16*)alloc(32768 * 2);
  _Float16* Wh2 = (_Float16*)alloc(16384 * 2);
  float* bzr = (float*)alloc(128 * 4);
  float* bhb = (float*)alloc(64 * 4);
  float* h = (float*)alloc((size_t)N * 64 * 4);
  _Float16* hh = (_Float16*)alloc((size_t)N * 64 * 2);
  _Float16* mv2h = (_Float16*)alloc((size_t)N * 64 * 2);
  _Float16* hrh = (_Float16*)alloc((size_t)N * 64 * 2);
  _Float16* zh = (_Float16*)alloc((size_t)N * 64 * 2);

  size_t need_big = 2 * ((size_t)N * T_STEPS * 64 * 2 + 255);
  bool big = (used + need_big + 4096) <= ws_size;
  _Float16 *xh_i = nullptr, *mvx_t = nullptr, *xth = nullptr, *mvxth = nullptr;
  if (big) {
    xh_i = (_Float16*)alloc((size_t)N * T_STEPS * 64 * 2);   // [N][T*64] interleaved
    mvx_t = (_Float16*)alloc((size_t)T_STEPS * N * 64 * 2);  // [T][N][64]
  } else {
    xth = (_Float16*)alloc((size_t)N * 64 * 2);
    mvxth = (_Float16*)alloc((size_t)N * 64 * 2);
  }

  hipMemsetAsync(deg, 0, (size_t)N * 4, stream);
  hipMemsetAsync(cnt, 0, (size_t)N * 4, stream);
  hipMemsetAsync(fill, 0, (size_t)N * 4, stream);
  hipMemsetAsync(h, 0, (size_t)N * 64 * 4, stream);
  hipMemsetAsync(hh, 0, (size_t)N * 64 * 2, stream);

  k_deg_cnt<<<(E + 255) / 256, 256, 0, stream>>>(ei, E, N, deg, cnt);
  k_dinv<<<(N + 255) / 256, 256, 0, stream>>>(deg, dinv, N);
  int nb = (N + 1023) / 1024;
  k_scan1<<<nb, 1024, 0, stream>>>(cnt, incl, bsum, N);
  if (nb <= 1024)
    k_scan2p<<<1, 1024, 0, stream>>>(bsum, boff, nb);
  else
    k_scan2<<<1, 1, 0, stream>>>(bsum, boff, nb);
  k_scan3<<<nb, 1024, 0, stream>>>(incl, cnt, boff, rp, N, E);
  k_fill<<<(E + 255) / 256, 256, 0, stream>>>(ei, E, N, dinv, rp, fill, cw);
  k_pack<<<(49152 + 192 + 255) / 256, 256, 0, stream>>>(Whz, Whr, Wxz, Wxr, Whh, Wxh,
                                                        bhz, bhr, bxz, bxr, bhh, bxh,
                                                        Wzr, Wh2, bzr, bhb);

  if (big) {
    int total = T_STEPS * N * 16;
    k_cvt_x<<<(total + 255) / 256, 256, 0, stream>>>(Xseq, xh_i, N, total);
    int half_n = (N + 1) / 2;
    k_spmv_x8<<<(half_n + 3) / 4, 256, 0, stream>>>(rp, cw, xh_i, mvx_t, 0, half_n, N);
    k_spmv_x8<<<(N - half_n + 3) / 4, 256, 0, stream>>>(rp, cw, xh_i, mvx_t, half_n,
                                                        N - half_n, N);
  }

  const int gb = (N + 63) / 64;
  for (int tt = 0; tt < T_STEPS; ++tt) {
    const float* xt = Xseq + (size_t)tt * N * F_DIM;
    const _Float16* A2;
    const _Float16* A3;
    int s2, s3;
    if (big) {
      A2 = xh_i + tt * 64; s2 = T_STEPS * 64;                // interleaved, stride 512
      A3 = mvx_t + (size_t)tt * N * 64; s3 = 64;             // contiguous slice
    } else {
      k_cvt1<<<(N * 16 + 255) / 256, 256, 0, stream>>>(xt, xth, N * 16);
      k_spmv_f32<<<(N + 3) / 4, 256, 0, stream>>>(rp, cw, xt, mvxth, N);
      A2 = xth; s2 = 64;
      A3 = mvxth; s3 = 64;
    }
    // mv(h)
    k_spmv4<<<(N + 3) / 4, 256, 0, stream>>>(rp, cw, hh, mv2h, N);
    // z and hr (one block, both chunks)
    k_gzr<<<gb, 512, 0, stream>>>(hh, mv2h, A2, s2, A3, s3, Wzr, bzr, zh, h, hrh, N);
    // mv(h*r)
    k_spmv4<<<(N + 3) / 4, 256, 0, stream>>>(rp, cw, hrh, mv2h, N);
    // h update
    k_gh<<<gb, 256, 0, stream>>>(hrh, mv2h, A2, s2, A3, s3, Wh2, bhb, zh, h, hh, N);
  }
  k_lin<<<(N + 15) / 16, 256, 0, stream>>>(h, Wlin, blin, out, N);
}